// Round 3
// baseline (562.634 us; speedup 1.0000x reference)
//
#include <hip/hip_runtime.h>

// SSD MultiBox loss, MI355X. B=32 batches, A=24564 anchors, C=81 classes, M=20 targets.
// Outputs: out[0]=class_loss, out[1]=loc_loss/N, out[2]=N  (fp32)

#define B_ 32
#define A_ 24564
#define C_ 81
#define M_ 20

constexpr float THRESH = 0.5f;
constexpr float VAR0 = 0.1f;
constexpr float VAR1 = 0.2f;
constexpr int GRIDX = (A_ + 63) / 64;     // 384 blocks in x, 64 anchors/block
constexpr int NBLK = GRIDX * B_;          // 12288 main blocks

// ---------------- K1: best anchor per (b, m) --------------------------------
// numpy argmax ties -> smallest index: pack (iou_bits, ~a) and take max.
__global__ __launch_bounds__(256) void k_best_anchor(
    const float* __restrict__ anchors, const float* __restrict__ targets,
    int* __restrict__ bestA) {
  int bm = blockIdx.x;                 // b*M + m
  const float* t = targets + (size_t)bm * 5;
  float tx0 = t[0], ty0 = t[1], tx1 = t[2], ty1 = t[3];
  float areaT = (tx1 - tx0) * (ty1 - ty0);
  unsigned long long best = 0ull;
  for (int a = threadIdx.x; a < A_; a += 256) {
    float4 an = ((const float4*)anchors)[a];
    float ax0 = an.x - an.z * 0.5f, ay0 = an.y - an.w * 0.5f;
    float ax1 = an.x + an.z * 0.5f, ay1 = an.y + an.w * 0.5f;
    float lx = fmaxf(tx0, ax0), ly = fmaxf(ty0, ay0);
    float rx = fminf(tx1, ax1), ry = fminf(ty1, ay1);
    float w = fmaxf(rx - lx, 0.0f), h = fmaxf(ry - ly, 0.0f);
    float inter = w * h;
    float iou = inter / (areaT + (ax1 - ax0) * (ay1 - ay0) - inter);
    unsigned long long key =
        ((unsigned long long)__float_as_uint(iou) << 32) |
        (unsigned long long)(0xFFFFFFFFu - (unsigned)a);
    best = (key > best) ? key : best;
  }
  __shared__ unsigned long long sh[256];
  sh[threadIdx.x] = best;
  __syncthreads();
  for (int s = 128; s > 0; s >>= 1) {
    if (threadIdx.x < s) {
      unsigned long long o = sh[threadIdx.x + s];
      if (o > sh[threadIdx.x]) sh[threadIdx.x] = o;
    }
    __syncthreads();
  }
  if (threadIdx.x == 0)
    bestA[bm] = (int)(0xFFFFFFFFu - (unsigned)(sh[0] & 0xFFFFFFFFull));
}

// ---------------- K2: match + CE + smooth-L1, 4 threads per anchor ----------
// Stages the block's 64 conf-rows (64*81 floats) into LDS with coalesced
// float4 loads (block base is 16B-aligned: (b*A + 64*blkx)*324 % 16 == 0),
// then does the class-split LSE from LDS. Stride-81 LDS reads are ~2-way
// bank aliased (free on CDNA4).
__global__ __launch_bounds__(256) void k_main(
    const float* __restrict__ pred_conf, const float* __restrict__ pred_loc,
    const float* __restrict__ anchors, const float* __restrict__ targets,
    const int* __restrict__ bestA, float* __restrict__ neg_ce,
    float* __restrict__ partLoc, float* __restrict__ partCe,
    int* __restrict__ posCount) {
  __shared__ float sRows[64 * C_];         // 20736 B
  __shared__ float sT[M_ * 5];
  __shared__ int sBA[M_];
  int b = blockIdx.y;
  int a0 = blockIdx.x * 64;

  if (threadIdx.x < M_ * 5) sT[threadIdx.x] = targets[(size_t)b * M_ * 5 + threadIdx.x];
  if (threadIdx.x < M_) sBA[threadIdx.x] = bestA[b * M_ + threadIdx.x];

  // stage rows [a0, a0+64) clamped to A_ (row counts 64 or 52: *81 % 4 == 0)
  int nf4 = (min(64, A_ - a0) * C_) >> 2;
  const float4* src = (const float4*)(pred_conf + ((size_t)b * A_ + a0) * C_);
  float4* dst = (float4*)sRows;
  for (int i = threadIdx.x; i < nf4; i += 256) dst[i] = src[i];
  __syncthreads();

  int g = threadIdx.x & 3;                 // class-split lane within group of 4
  int q = threadIdx.x >> 2;                // anchor slot within block
  int a = a0 + q;
  bool active = (a < A_);

  float myCe = 0.0f, myLoc = 0.0f;
  int myPos = 0;

  if (active) {
    float4 an = ((const float4*)anchors)[a];
    float ax0 = an.x - an.z * 0.5f, ay0 = an.y - an.w * 0.5f;
    float ax1 = an.x + an.z * 0.5f, ay1 = an.y + an.w * 0.5f;
    float areaA = (ax1 - ax0) * (ay1 - ay0);

    // argmax over M targets (first-max wins via strict >)
    float bestIou = -1.0f; int bestM = 0;
    #pragma unroll
    for (int m = 0; m < M_; ++m) {
      float tx0 = sT[m * 5 + 0], ty0 = sT[m * 5 + 1];
      float tx1 = sT[m * 5 + 2], ty1 = sT[m * 5 + 3];
      float lx = fmaxf(tx0, ax0), ly = fmaxf(ty0, ay0);
      float rx = fminf(tx1, ax1), ry = fminf(ty1, ay1);
      float w = fmaxf(rx - lx, 0.0f), h = fmaxf(ry - ly, 0.0f);
      float inter = w * h;
      float areaT = (tx1 - tx0) * (ty1 - ty0);
      float iou = inter / (areaT + areaA - inter);
      if (iou > bestIou) { bestIou = iou; bestM = m; }
    }
    // guarantee override, ascending m => last-m-wins (numpy scatter semantics)
    #pragma unroll
    for (int m = 0; m < M_; ++m)
      if (sBA[m] == a) { bestIou = 2.0f; bestM = m; }

    bool pos = (bestIou >= THRESH);
    int c = pos ? ((int)sT[bestM * 5 + 4] + 1) : 0;   // class index in [0,80]

    // log-sum-exp over 81 classes split across 4 lanes (static reg indexing)
    const float* row = sRows + q * C_;
    float x[20];
    #pragma unroll
    for (int k = 0; k < 20; ++k) x[k] = row[g + 4 * k];
    float r80 = row[80];
    float v80 = (g == 0) ? r80 : -1e30f;

    float xm = v80;
    #pragma unroll
    for (int k = 0; k < 20; ++k) xm = fmaxf(xm, x[k]);
    xm = fmaxf(xm, __shfl_xor(xm, 1, 64));
    xm = fmaxf(xm, __shfl_xor(xm, 2, 64));

    float s = __expf(v80 - xm);
    #pragma unroll
    for (int k = 0; k < 20; ++k) s += __expf(x[k] - xm);
    s += __shfl_xor(s, 1, 64);
    s += __shfl_xor(s, 2, 64);

    float xc = 0.0f;
    #pragma unroll
    for (int k = 0; k < 20; ++k)
      if (g + 4 * k == c) xc = x[k];
    if (c == 80) xc = (g == 0) ? r80 : 0.0f;
    xc += __shfl_xor(xc, 1, 64);
    xc += __shfl_xor(xc, 2, 64);

    float ce = xm + __logf(s) - xc;

    if (g == 0) {
      neg_ce[(size_t)b * A_ + a] = pos ? -1.0f : ce;
      if (pos) {
        myPos = 1;
        myCe = ce;
        float4 pl = ((const float4*)pred_loc)[(size_t)b * A_ + a];
        float mx0 = sT[bestM * 5 + 0], my0 = sT[bestM * 5 + 1];
        float mx1 = sT[bestM * 5 + 2], my1 = sT[bestM * 5 + 3];
        float gcx = ((mx0 + mx1) * 0.5f - an.x) / (VAR0 * an.z);
        float gcy = ((my0 + my1) * 0.5f - an.y) / (VAR0 * an.w);
        float gw  = __logf((mx1 - mx0) / an.z) / VAR1;
        float gh  = __logf((my1 - my0) / an.w) / VAR1;
        float d0 = fabsf(pl.x - gcx), d1 = fabsf(pl.y - gcy);
        float d2 = fabsf(pl.z - gw),  d3 = fabsf(pl.w - gh);
        float s0 = d0 < 1.0f ? 0.5f * d0 * d0 : d0 - 0.5f;
        float s1 = d1 < 1.0f ? 0.5f * d1 * d1 : d1 - 0.5f;
        float s2 = d2 < 1.0f ? 0.5f * d2 * d2 : d2 - 0.5f;
        float s3 = d3 < 1.0f ? 0.5f * d3 * d3 : d3 - 0.5f;
        myLoc = s0 + s1 + s2 + s3;
      }
    }
  }

  // block reduce (wave shfl + LDS across 4 waves); partials avoid float atomics
  float rc = myCe, rl = myLoc; int rp = myPos;
  #pragma unroll
  for (int off = 32; off > 0; off >>= 1) {
    rc += __shfl_down(rc, off, 64);
    rl += __shfl_down(rl, off, 64);
    rp += __shfl_down(rp, off, 64);
  }
  __shared__ float swc[4], swl[4];
  __shared__ int swp[4];
  int w = threadIdx.x >> 6;
  if ((threadIdx.x & 63) == 0) { swc[w] = rc; swl[w] = rl; swp[w] = rp; }
  __syncthreads();
  if (threadIdx.x == 0) {
    float tc = swc[0] + swc[1] + swc[2] + swc[3];
    float tl = swl[0] + swl[1] + swl[2] + swl[3];
    int tp = swp[0] + swp[1] + swp[2] + swp[3];
    int pb = blockIdx.y * gridDim.x + blockIdx.x;
    partCe[pb] = tc;
    partLoc[pb] = tl;
    if (tp) atomicAdd(&posCount[b], tp);
  }
}

// ---------------- K3: per-batch exact top-K sum, 3-pass radix (11/11/10) ----
// Per pass: histogram count AND value-sum per bin; bins strictly above the
// boundary digit are entirely inside the top-K, so their sums accumulate
// directly -> no separate final sum scan. Ends with Krem copies of the exact
// K-th value vk.
__global__ __launch_bounds__(256) void k_select(
    const float* __restrict__ neg_ce, const int* __restrict__ posCount,
    float* __restrict__ negSumB) {
  int b = blockIdx.x;
  int tid = threadIdx.x;
  const float* v = neg_ce + (size_t)b * A_;
  int p = posCount[b];
  int cand = A_ - p;
  int K = max(10, min(p * 3, A_ - p));
  if (K > cand) K = cand;
  if (K <= 0) { if (tid == 0) negSumB[b] = 0.0f; return; }

  __shared__ int hist[2048];
  __shared__ float hsum[2048];
  __shared__ int sC8[256];
  __shared__ float sS8[256];
  __shared__ unsigned shPrefix;
  __shared__ int shKrem;
  __shared__ float shSum;

  unsigned prefix = 0;
  int Krem = K;
  float sumAcc = 0.0f;

  const int shifts[3] = {21, 10, 0};
  const int widths[3] = {11, 11, 10};

  for (int pass = 0; pass < 3; ++pass) {
    int shift = shifts[pass], width = widths[pass];
    int nb = 1 << width;
    for (int i = tid; i < nb; i += 256) { hist[i] = 0; hsum[i] = 0.0f; }
    __syncthreads();
    for (int i = tid; i < A_; i += 256) {
      float f = v[i];
      if (f >= 0.0f) {                       // positives marked -1.0f; ce >= 0
        unsigned u = __float_as_uint(f);
        bool m = (pass == 0) || ((u >> (shift + width)) == prefix);
        if (m) {
          unsigned d = (u >> shift) & (unsigned)(nb - 1);
          atomicAdd(&hist[d], 1);
          atomicAdd(&hsum[d], f);
        }
      }
    }
    __syncthreads();
    int per = nb >> 8;                       // 8 or 4 bins per thread
    int c8 = 0; float s8 = 0.0f;
    for (int i = 0; i < per; ++i) { c8 += hist[tid * per + i]; s8 += hsum[tid * per + i]; }
    sC8[tid] = c8; sS8[tid] = s8;
    __syncthreads();
    if (tid == 0) {
      int cum = 0; float sa = 0.0f; int t;
      for (t = 255; t >= 0; --t) {
        if (cum + sC8[t] >= Krem) break;
        cum += sC8[t]; sa += sS8[t];
      }
      int d = t * per;
      for (int i = per - 1; i >= 0; --i) {
        int bin = t * per + i;
        if (cum + hist[bin] >= Krem) { d = bin; break; }
        cum += hist[bin]; sa += hsum[bin];
      }
      shPrefix = (prefix << width) | (unsigned)d;
      shKrem = Krem - cum;
      shSum = sumAcc + sa;
    }
    __syncthreads();
    prefix = shPrefix; Krem = shKrem; sumAcc = shSum;
    __syncthreads();
  }

  if (tid == 0)
    negSumB[b] = sumAcc + (float)Krem * __uint_as_float(prefix);
}

// ---------------- K4: finalize ---------------------------------------------
__global__ __launch_bounds__(256) void k_final(
    const int* __restrict__ posCount, const float* __restrict__ partLoc,
    const float* __restrict__ partCe, const float* __restrict__ negSumB,
    float* __restrict__ out) {
  double locS = 0.0, ceS = 0.0, negS = 0.0;
  int N = 0;
  for (int i = threadIdx.x; i < NBLK; i += 256) {
    locS += (double)partLoc[i];
    ceS  += (double)partCe[i];
  }
  if (threadIdx.x < B_) {
    N = posCount[threadIdx.x];
    negS = (double)negSumB[threadIdx.x];
  }
  #pragma unroll
  for (int off = 32; off > 0; off >>= 1) {
    locS += __shfl_down(locS, off, 64);
    ceS  += __shfl_down(ceS, off, 64);
    negS += __shfl_down(negS, off, 64);
    N    += __shfl_down(N, off, 64);
  }
  __shared__ double sL[4], sC[4], sG[4];
  __shared__ int sN[4];
  int w = threadIdx.x >> 6;
  if ((threadIdx.x & 63) == 0) { sL[w] = locS; sC[w] = ceS; sG[w] = negS; sN[w] = N; }
  __syncthreads();
  if (threadIdx.x == 0) {
    double L = sL[0] + sL[1] + sL[2] + sL[3];
    double Cc = sC[0] + sC[1] + sC[2] + sC[3];
    double G = sG[0] + sG[1] + sG[2] + sG[3];
    int n = sN[0] + sN[1] + sN[2] + sN[3];
    float fn = (float)n;
    out[0] = (float)((Cc + G) / (double)fn);
    out[1] = (float)(L / (double)fn);
    out[2] = fn;
  }
}

extern "C" void kernel_launch(void* const* d_in, const int* in_sizes, int n_in,
                              void* d_out, int out_size, void* d_ws, size_t ws_size,
                              hipStream_t stream) {
  const float* pred_conf = (const float*)d_in[0];
  const float* pred_loc  = (const float*)d_in[1];
  const float* anchors   = (const float*)d_in[2];
  const float* targets   = (const float*)d_in[3];
  float* out = (float*)d_out;

  char* ws = (char*)d_ws;
  int*   posCount = (int*)(ws + 0);                    // 128 B
  int*   bestA    = (int*)(ws + 128);                  // 2560 B
  float* partLoc  = (float*)(ws + 4096);               // 48 KiB
  float* partCe   = (float*)(ws + 4096 + 49152);       // 48 KiB
  float* negSumB  = (float*)(ws + 4096 + 2 * 49152);   // 128 B
  float* neg_ce   = (float*)(ws + 131072);             // B*A floats ~3.1 MiB

  hipMemsetAsync(ws, 0, 4096, stream);                 // zero posCount

  k_best_anchor<<<dim3(B_ * M_), 256, 0, stream>>>(anchors, targets, bestA);
  k_main<<<dim3(GRIDX, B_), 256, 0, stream>>>(pred_conf, pred_loc, anchors, targets,
                                              bestA, neg_ce, partLoc, partCe, posCount);
  k_select<<<dim3(B_), 256, 0, stream>>>(neg_ce, posCount, negSumB);
  k_final<<<1, 256, 0, stream>>>(posCount, partLoc, partCe, negSumB, out);
}

// Round 4
// 561.218 us; speedup vs baseline: 1.0025x; 1.0025x over previous
//
#include <hip/hip_runtime.h>

// SSD MultiBox loss, MI355X. B=32 batches, A=24564 anchors, C=81 classes, M=20 targets.
// Outputs: out[0]=class_loss, out[1]=loc_loss/N, out[2]=N  (fp32)
// 3 dispatches: k_best (also zeros control slots) -> k_main -> k_select(+fused final).

#define B_ 32
#define A_ 24564
#define C_ 81
#define M_ 20

constexpr float THRESH = 0.5f;
constexpr float VAR0 = 0.1f;
constexpr float VAR1 = 0.2f;
constexpr int GRIDX = (A_ + 63) / 64;     // 384 blocks in x, 64 anchors/block
constexpr int NBLK = GRIDX * B_;          // 12288 main blocks

// ---------------- K1: best anchor per (b, m); block 0 zeros control slots ---
// numpy argmax ties -> smallest index: pack (iou_bits, ~a) and take max.
__global__ __launch_bounds__(256) void k_best_anchor(
    const float* __restrict__ anchors, const float* __restrict__ targets,
    int* __restrict__ bestA, int* __restrict__ posCount,
    int* __restrict__ doneCount, float* __restrict__ negAccum) {
  int bm = blockIdx.x;                 // b*M + m
  if (bm == 0) {                       // zero control state for this call
    if (threadIdx.x < B_) posCount[threadIdx.x] = 0;
    if (threadIdx.x == B_) *doneCount = 0;
    if (threadIdx.x == B_ + 1) *negAccum = 0.0f;
  }
  const float* t = targets + (size_t)bm * 5;
  float tx0 = t[0], ty0 = t[1], tx1 = t[2], ty1 = t[3];
  float areaT = (tx1 - tx0) * (ty1 - ty0);
  unsigned long long best = 0ull;
  for (int a = threadIdx.x; a < A_; a += 256) {
    float4 an = ((const float4*)anchors)[a];
    float ax0 = an.x - an.z * 0.5f, ay0 = an.y - an.w * 0.5f;
    float ax1 = an.x + an.z * 0.5f, ay1 = an.y + an.w * 0.5f;
    float lx = fmaxf(tx0, ax0), ly = fmaxf(ty0, ay0);
    float rx = fminf(tx1, ax1), ry = fminf(ty1, ay1);
    float w = fmaxf(rx - lx, 0.0f), h = fmaxf(ry - ly, 0.0f);
    float inter = w * h;
    float iou = inter / (areaT + (ax1 - ax0) * (ay1 - ay0) - inter);
    unsigned long long key =
        ((unsigned long long)__float_as_uint(iou) << 32) |
        (unsigned long long)(0xFFFFFFFFu - (unsigned)a);
    best = (key > best) ? key : best;
  }
  __shared__ unsigned long long sh[256];
  sh[threadIdx.x] = best;
  __syncthreads();
  for (int s = 128; s > 0; s >>= 1) {
    if (threadIdx.x < s) {
      unsigned long long o = sh[threadIdx.x + s];
      if (o > sh[threadIdx.x]) sh[threadIdx.x] = o;
    }
    __syncthreads();
  }
  if (threadIdx.x == 0)
    bestA[bm] = (int)(0xFFFFFFFFu - (unsigned)(sh[0] & 0xFFFFFFFFull));
}

// ---------------- K2: match + CE + smooth-L1, 4 threads per anchor ----------
// Stages the block's 64 conf-rows into LDS with coalesced float4 loads, then
// class-split LSE from LDS (stride-81 reads = 2-way bank alias, free on CDNA4).
// HBM-floor bound: one 255 MB pass over pred_conf.
__global__ __launch_bounds__(256) void k_main(
    const float* __restrict__ pred_conf, const float* __restrict__ pred_loc,
    const float* __restrict__ anchors, const float* __restrict__ targets,
    const int* __restrict__ bestA, float* __restrict__ neg_ce,
    float* __restrict__ partLoc, float* __restrict__ partCe,
    int* __restrict__ posCount) {
  __shared__ float sRows[64 * C_];         // 20736 B
  __shared__ float sT[M_ * 5];
  __shared__ int sBA[M_];
  int b = blockIdx.y;
  int a0 = blockIdx.x * 64;

  if (threadIdx.x < M_ * 5) sT[threadIdx.x] = targets[(size_t)b * M_ * 5 + threadIdx.x];
  if (threadIdx.x < M_) sBA[threadIdx.x] = bestA[b * M_ + threadIdx.x];

  // stage rows [a0, a0+64) clamped to A_ (row counts 64 or 52: *81 % 4 == 0)
  int nf4 = (min(64, A_ - a0) * C_) >> 2;
  const float4* src = (const float4*)(pred_conf + ((size_t)b * A_ + a0) * C_);
  float4* dst = (float4*)sRows;
  for (int i = threadIdx.x; i < nf4; i += 256) dst[i] = src[i];
  __syncthreads();

  int g = threadIdx.x & 3;                 // class-split lane within group of 4
  int q = threadIdx.x >> 2;                // anchor slot within block
  int a = a0 + q;
  bool active = (a < A_);

  float myCe = 0.0f, myLoc = 0.0f;
  int myPos = 0;

  if (active) {
    float4 an = ((const float4*)anchors)[a];
    float ax0 = an.x - an.z * 0.5f, ay0 = an.y - an.w * 0.5f;
    float ax1 = an.x + an.z * 0.5f, ay1 = an.y + an.w * 0.5f;
    float areaA = (ax1 - ax0) * (ay1 - ay0);

    // argmax over M targets (first-max wins via strict >)
    float bestIou = -1.0f; int bestM = 0;
    #pragma unroll
    for (int m = 0; m < M_; ++m) {
      float tx0 = sT[m * 5 + 0], ty0 = sT[m * 5 + 1];
      float tx1 = sT[m * 5 + 2], ty1 = sT[m * 5 + 3];
      float lx = fmaxf(tx0, ax0), ly = fmaxf(ty0, ay0);
      float rx = fminf(tx1, ax1), ry = fminf(ty1, ay1);
      float w = fmaxf(rx - lx, 0.0f), h = fmaxf(ry - ly, 0.0f);
      float inter = w * h;
      float areaT = (tx1 - tx0) * (ty1 - ty0);
      float iou = inter / (areaT + areaA - inter);
      if (iou > bestIou) { bestIou = iou; bestM = m; }
    }
    // guarantee override, ascending m => last-m-wins (numpy scatter semantics)
    #pragma unroll
    for (int m = 0; m < M_; ++m)
      if (sBA[m] == a) { bestIou = 2.0f; bestM = m; }

    bool pos = (bestIou >= THRESH);
    int c = pos ? ((int)sT[bestM * 5 + 4] + 1) : 0;   // class index in [0,80]

    // log-sum-exp over 81 classes split across 4 lanes (static reg indexing)
    const float* row = sRows + q * C_;
    float x[20];
    #pragma unroll
    for (int k = 0; k < 20; ++k) x[k] = row[g + 4 * k];
    float r80 = row[80];
    float v80 = (g == 0) ? r80 : -1e30f;

    float xm = v80;
    #pragma unroll
    for (int k = 0; k < 20; ++k) xm = fmaxf(xm, x[k]);
    xm = fmaxf(xm, __shfl_xor(xm, 1, 64));
    xm = fmaxf(xm, __shfl_xor(xm, 2, 64));

    float s = __expf(v80 - xm);
    #pragma unroll
    for (int k = 0; k < 20; ++k) s += __expf(x[k] - xm);
    s += __shfl_xor(s, 1, 64);
    s += __shfl_xor(s, 2, 64);

    float xc = 0.0f;
    #pragma unroll
    for (int k = 0; k < 20; ++k)
      if (g + 4 * k == c) xc = x[k];
    if (c == 80) xc = (g == 0) ? r80 : 0.0f;
    xc += __shfl_xor(xc, 1, 64);
    xc += __shfl_xor(xc, 2, 64);

    float ce = xm + __logf(s) - xc;

    if (g == 0) {
      neg_ce[(size_t)b * A_ + a] = pos ? -1.0f : ce;
      if (pos) {
        myPos = 1;
        myCe = ce;
        float4 pl = ((const float4*)pred_loc)[(size_t)b * A_ + a];
        float mx0 = sT[bestM * 5 + 0], my0 = sT[bestM * 5 + 1];
        float mx1 = sT[bestM * 5 + 2], my1 = sT[bestM * 5 + 3];
        float gcx = ((mx0 + mx1) * 0.5f - an.x) / (VAR0 * an.z);
        float gcy = ((my0 + my1) * 0.5f - an.y) / (VAR0 * an.w);
        float gw  = __logf((mx1 - mx0) / an.z) / VAR1;
        float gh  = __logf((my1 - my0) / an.w) / VAR1;
        float d0 = fabsf(pl.x - gcx), d1 = fabsf(pl.y - gcy);
        float d2 = fabsf(pl.z - gw),  d3 = fabsf(pl.w - gh);
        float s0 = d0 < 1.0f ? 0.5f * d0 * d0 : d0 - 0.5f;
        float s1 = d1 < 1.0f ? 0.5f * d1 * d1 : d1 - 0.5f;
        float s2 = d2 < 1.0f ? 0.5f * d2 * d2 : d2 - 0.5f;
        float s3 = d3 < 1.0f ? 0.5f * d3 * d3 : d3 - 0.5f;
        myLoc = s0 + s1 + s2 + s3;
      }
    }
  }

  // block reduce (wave shfl + LDS across 4 waves); partials avoid float atomics
  float rc = myCe, rl = myLoc; int rp = myPos;
  #pragma unroll
  for (int off = 32; off > 0; off >>= 1) {
    rc += __shfl_down(rc, off, 64);
    rl += __shfl_down(rl, off, 64);
    rp += __shfl_down(rp, off, 64);
  }
  __shared__ float swc[4], swl[4];
  __shared__ int swp[4];
  int w = threadIdx.x >> 6;
  if ((threadIdx.x & 63) == 0) { swc[w] = rc; swl[w] = rl; swp[w] = rp; }
  __syncthreads();
  if (threadIdx.x == 0) {
    float tc = swc[0] + swc[1] + swc[2] + swc[3];
    float tl = swl[0] + swl[1] + swl[2] + swl[3];
    int tp = swp[0] + swp[1] + swp[2] + swp[3];
    int pb = blockIdx.y * gridDim.x + blockIdx.x;
    partCe[pb] = tc;
    partLoc[pb] = tl;
    if (tp) atomicAdd(&posCount[b], tp);
  }
}

// ---------------- K3: per-batch exact top-K sum + fused finalize ------------
// 3-pass radix (11/11/10) with fused per-bin count+sum. Each block atomicAdds
// its batch sum into *negAccum (device-scope, coherent); the LAST block to
// finish (doneCount) performs the final reduction. partLoc/partCe/posCount
// were written by the PREVIOUS kernel -> coherent at dispatch boundary.
__global__ __launch_bounds__(256) void k_select(
    const float* __restrict__ neg_ce, const int* __restrict__ posCount,
    const float* __restrict__ partLoc, const float* __restrict__ partCe,
    int* __restrict__ doneCount, float* __restrict__ negAccum,
    float* __restrict__ out) {
  int b = blockIdx.x;
  int tid = threadIdx.x;
  const float* v = neg_ce + (size_t)b * A_;
  int p = posCount[b];
  int cand = A_ - p;
  int K = max(10, min(p * 3, A_ - p));
  if (K > cand) K = cand;

  __shared__ int hist[2048];
  __shared__ float hsum[2048];
  __shared__ int sC8[256];
  __shared__ float sS8[256];
  __shared__ unsigned shPrefix;
  __shared__ int shKrem;
  __shared__ float shSum;
  __shared__ int shAmLast;

  unsigned prefix = 0;
  int Krem = K;
  float sumAcc = 0.0f;

  const int shifts[3] = {21, 10, 0};
  const int widths[3] = {11, 11, 10};

  for (int pass = 0; pass < 3; ++pass) {
    int shift = shifts[pass], width = widths[pass];
    int nb = 1 << width;
    for (int i = tid; i < nb; i += 256) { hist[i] = 0; hsum[i] = 0.0f; }
    __syncthreads();
    for (int i = tid; i < A_; i += 256) {
      float f = v[i];
      if (f >= 0.0f) {                       // positives marked -1.0f; ce >= 0
        unsigned u = __float_as_uint(f);
        bool m = (pass == 0) || ((u >> (shift + width)) == prefix);
        if (m) {
          unsigned d = (u >> shift) & (unsigned)(nb - 1);
          atomicAdd(&hist[d], 1);
          atomicAdd(&hsum[d], f);
        }
      }
    }
    __syncthreads();
    int per = nb >> 8;                       // 8 or 4 bins per thread
    int c8 = 0; float s8 = 0.0f;
    for (int i = 0; i < per; ++i) { c8 += hist[tid * per + i]; s8 += hsum[tid * per + i]; }
    sC8[tid] = c8; sS8[tid] = s8;
    __syncthreads();
    if (tid == 0) {
      int cum = 0; float sa = 0.0f; int t;
      for (t = 255; t >= 0; --t) {
        if (cum + sC8[t] >= Krem) break;
        cum += sC8[t]; sa += sS8[t];
      }
      int d = t * per;
      for (int i = per - 1; i >= 0; --i) {
        int bin = t * per + i;
        if (cum + hist[bin] >= Krem) { d = bin; break; }
        cum += hist[bin]; sa += hsum[bin];
      }
      shPrefix = (prefix << width) | (unsigned)d;
      shKrem = Krem - cum;
      shSum = sumAcc + sa;
    }
    __syncthreads();
    prefix = shPrefix; Krem = shKrem; sumAcc = shSum;
    __syncthreads();
  }

  if (tid == 0) {
    float batchSum = sumAcc + (float)Krem * __uint_as_float(prefix);
    atomicAdd(negAccum, batchSum);
    __threadfence();                         // release: negAccum before done tick
    int prev = atomicAdd(doneCount, 1);
    shAmLast = (prev == B_ - 1) ? 1 : 0;
  }
  __syncthreads();

  if (shAmLast) {
    __threadfence();                         // acquire
    double locS = 0.0, ceS = 0.0;
    int N = 0;
    for (int i = tid; i < NBLK; i += 256) {
      locS += (double)partLoc[i];
      ceS  += (double)partCe[i];
    }
    if (tid < B_) N = posCount[tid];
    #pragma unroll
    for (int off = 32; off > 0; off >>= 1) {
      locS += __shfl_down(locS, off, 64);
      ceS  += __shfl_down(ceS, off, 64);
      N    += __shfl_down(N, off, 64);
    }
    __shared__ double sL[4], sC[4];
    __shared__ int sN[4];
    int w = tid >> 6;
    if ((tid & 63) == 0) { sL[w] = locS; sC[w] = ceS; sN[w] = N; }
    __syncthreads();
    if (tid == 0) {
      double L = sL[0] + sL[1] + sL[2] + sL[3];
      double Cc = sC[0] + sC[1] + sC[2] + sC[3];
      int n = sN[0] + sN[1] + sN[2] + sN[3];
      float G = atomicAdd(negAccum, 0.0f);   // coherent read of all 32 adds
      float fn = (float)n;
      out[0] = (float)((Cc + (double)G) / (double)fn);
      out[1] = (float)(L / (double)fn);
      out[2] = fn;
    }
  }
}

extern "C" void kernel_launch(void* const* d_in, const int* in_sizes, int n_in,
                              void* d_out, int out_size, void* d_ws, size_t ws_size,
                              hipStream_t stream) {
  const float* pred_conf = (const float*)d_in[0];
  const float* pred_loc  = (const float*)d_in[1];
  const float* anchors   = (const float*)d_in[2];
  const float* targets   = (const float*)d_in[3];
  float* out = (float*)d_out;

  char* ws = (char*)d_ws;
  int*   posCount  = (int*)(ws + 0);                   // 128 B
  int*   doneCount = (int*)(ws + 128);                 // 4 B
  float* negAccum  = (float*)(ws + 132);               // 4 B
  int*   bestA     = (int*)(ws + 256);                 // 2560 B
  float* partLoc   = (float*)(ws + 4096);              // 48 KiB
  float* partCe    = (float*)(ws + 4096 + 49152);      // 48 KiB
  float* neg_ce    = (float*)(ws + 131072);            // B*A floats ~3.1 MiB

  k_best_anchor<<<dim3(B_ * M_), 256, 0, stream>>>(anchors, targets, bestA,
                                                   posCount, doneCount, negAccum);
  k_main<<<dim3(GRIDX, B_), 256, 0, stream>>>(pred_conf, pred_loc, anchors, targets,
                                              bestA, neg_ce, partLoc, partCe, posCount);
  k_select<<<dim3(B_), 256, 0, stream>>>(neg_ce, posCount, partLoc, partCe,
                                         doneCount, negAccum, out);
}

// Round 5
// 549.580 us; speedup vs baseline: 1.0238x; 1.0212x over previous
//
#include <hip/hip_runtime.h>

// SSD MultiBox loss, MI355X. B=32 batches, A=24564 anchors, C=81 classes, M=20 targets.
// Outputs: out[0]=class_loss, out[1]=loc_loss/N, out[2]=N  (fp32)
// 3 dispatches: k_best (also zeros control slots) -> k_main -> k_select(+fused final).

#define B_ 32
#define A_ 24564
#define C_ 81
#define M_ 20

constexpr float THRESH = 0.5f;
constexpr float VAR0 = 0.1f;
constexpr float VAR1 = 0.2f;
constexpr int GRIDX = (A_ + 63) / 64;     // 384 blocks in x, 64 anchors/block
constexpr int NBLK = GRIDX * B_;          // 12288 main blocks

// ---------------- K1: best anchor per (b, m); block 0 zeros control slots ---
// numpy argmax ties -> smallest index: pack (iou_bits, ~a) and take max.
__global__ __launch_bounds__(256) void k_best_anchor(
    const float* __restrict__ anchors, const float* __restrict__ targets,
    int* __restrict__ bestA, int* __restrict__ posCount,
    int* __restrict__ doneCount, float* __restrict__ negAccum) {
  int bm = blockIdx.x;                 // b*M + m
  if (bm == 0) {                       // zero control state for this call
    if (threadIdx.x < B_) posCount[threadIdx.x] = 0;
    if (threadIdx.x == B_) *doneCount = 0;
    if (threadIdx.x == B_ + 1) *negAccum = 0.0f;
  }
  const float* t = targets + (size_t)bm * 5;
  float tx0 = t[0], ty0 = t[1], tx1 = t[2], ty1 = t[3];
  float areaT = (tx1 - tx0) * (ty1 - ty0);
  unsigned long long best = 0ull;
  for (int a = threadIdx.x; a < A_; a += 256) {
    float4 an = ((const float4*)anchors)[a];
    float ax0 = an.x - an.z * 0.5f, ay0 = an.y - an.w * 0.5f;
    float ax1 = an.x + an.z * 0.5f, ay1 = an.y + an.w * 0.5f;
    float lx = fmaxf(tx0, ax0), ly = fmaxf(ty0, ay0);
    float rx = fminf(tx1, ax1), ry = fminf(ty1, ay1);
    float w = fmaxf(rx - lx, 0.0f), h = fmaxf(ry - ly, 0.0f);
    float inter = w * h;
    float iou = inter / (areaT + (ax1 - ax0) * (ay1 - ay0) - inter);
    unsigned long long key =
        ((unsigned long long)__float_as_uint(iou) << 32) |
        (unsigned long long)(0xFFFFFFFFu - (unsigned)a);
    best = (key > best) ? key : best;
  }
  __shared__ unsigned long long sh[256];
  sh[threadIdx.x] = best;
  __syncthreads();
  for (int s = 128; s > 0; s >>= 1) {
    if (threadIdx.x < s) {
      unsigned long long o = sh[threadIdx.x + s];
      if (o > sh[threadIdx.x]) sh[threadIdx.x] = o;
    }
    __syncthreads();
  }
  if (threadIdx.x == 0)
    bestA[bm] = (int)(0xFFFFFFFFu - (unsigned)(sh[0] & 0xFFFFFFFFull));
}

// ---------------- K2: match + CE + smooth-L1, 4 threads per anchor ----------
// Staging now uses async global_load_lds (width=16): up to 6 in-flight issues
// per thread, one drain at the barrier -- removes the serialized per-iteration
// vmcnt(0) chain that made R4's k_main latency-bound (162us @ 10% HBM).
// IoU matching is lane-split (5 targets/lane) + packed-u64 reduce; xc comes
// from a direct LDS broadcast read. Both bit-exact vs the previous version.
__global__ __launch_bounds__(256) void k_main(
    const float* __restrict__ pred_conf, const float* __restrict__ pred_loc,
    const float* __restrict__ anchors, const float* __restrict__ targets,
    const int* __restrict__ bestA, float* __restrict__ neg_ce,
    float* __restrict__ partLoc, float* __restrict__ partCe,
    int* __restrict__ posCount) {
  __shared__ float sRows[64 * C_];         // 20736 B
  __shared__ float sT[M_ * 5];
  __shared__ int sBA[M_];
  int b = blockIdx.y;
  int a0 = blockIdx.x * 64;
  int tid = threadIdx.x;

  if (tid < M_ * 5) sT[tid] = targets[(size_t)b * M_ * 5 + tid];
  if (tid < M_) sBA[tid] = bestA[b * M_ + tid];

  // async stage rows [a0, a0+64) clamped to A_ (nf4 = 1296 or 1053)
  int nf4 = (min(64, A_ - a0) * C_) >> 2;
  const float4* src = (const float4*)(pred_conf + ((size_t)b * A_ + a0) * C_);
  #pragma unroll
  for (int j = 0; j < 6; ++j) {
    int idx = j * 256 + tid;
    if (idx < nf4) {
      __builtin_amdgcn_global_load_lds(
          (const __attribute__((address_space(1))) unsigned int*)(src + idx),
          (__attribute__((address_space(3))) unsigned int*)(sRows + idx * 4),
          16, 0, 0);
    }
  }
  __syncthreads();                         // drains vmcnt + lds visibility

  int g = tid & 3;                         // class-split lane within group of 4
  int q = tid >> 2;                        // anchor slot within block
  int a = a0 + q;
  bool active = (a < A_);

  float myCe = 0.0f, myLoc = 0.0f;
  int myPos = 0;

  if (active) {
    float4 an = ((const float4*)anchors)[a];
    float ax0 = an.x - an.z * 0.5f, ay0 = an.y - an.w * 0.5f;
    float ax1 = an.x + an.z * 0.5f, ay1 = an.y + an.w * 0.5f;
    float areaA = (ax1 - ax0) * (ay1 - ay0);

    // lane-split argmax over M: lane g handles m = g, g+4, ..., g+16.
    // key = (iou_bits<<32) | ~m  -> max picks largest iou, ties -> smallest m
    // (== numpy first-max). Reduced across the 4-lane group via shfl_xor.
    unsigned long long key = 0ull;
    #pragma unroll
    for (int k = 0; k < 5; ++k) {
      int m = g + 4 * k;
      float tx0 = sT[m * 5 + 0], ty0 = sT[m * 5 + 1];
      float tx1 = sT[m * 5 + 2], ty1 = sT[m * 5 + 3];
      float lx = fmaxf(tx0, ax0), ly = fmaxf(ty0, ay0);
      float rx = fminf(tx1, ax1), ry = fminf(ty1, ay1);
      float w = fmaxf(rx - lx, 0.0f), h = fmaxf(ry - ly, 0.0f);
      float inter = w * h;
      float areaT = (tx1 - tx0) * (ty1 - ty0);
      float iou = inter / (areaT + areaA - inter);
      unsigned long long kk =
          ((unsigned long long)__float_as_uint(iou) << 32) |
          (unsigned long long)(0xFFFFFFFFu - (unsigned)m);
      key = (kk > key) ? kk : key;
    }
    {
      unsigned long long o = __shfl_xor(key, 1, 64);
      key = (o > key) ? o : key;
      o = __shfl_xor(key, 2, 64);
      key = (o > key) ? o : key;
    }
    float bestIou = __uint_as_float((unsigned)(key >> 32));
    int bestM = (int)(0xFFFFFFFFu - (unsigned)(key & 0xFFFFFFFFull));

    // guarantee override, ascending m => last-m-wins (numpy scatter semantics)
    #pragma unroll
    for (int m = 0; m < M_; ++m)
      if (sBA[m] == a) { bestIou = 2.0f; bestM = m; }

    bool pos = (bestIou >= THRESH);
    int c = pos ? ((int)sT[bestM * 5 + 4] + 1) : 0;   // class index in [0,80]

    // log-sum-exp over 81 classes split across 4 lanes (static reg indexing)
    const float* row = sRows + q * C_;
    float x[20];
    #pragma unroll
    for (int k = 0; k < 20; ++k) x[k] = row[g + 4 * k];
    float r80 = row[80];
    float v80 = (g == 0) ? r80 : -1e30f;

    float xm = v80;
    #pragma unroll
    for (int k = 0; k < 20; ++k) xm = fmaxf(xm, x[k]);
    xm = fmaxf(xm, __shfl_xor(xm, 1, 64));
    xm = fmaxf(xm, __shfl_xor(xm, 2, 64));

    float s = __expf(v80 - xm);
    #pragma unroll
    for (int k = 0; k < 20; ++k) s += __expf(x[k] - xm);
    s += __shfl_xor(s, 1, 64);
    s += __shfl_xor(s, 2, 64);

    float xc = row[c];                     // LDS broadcast (4 lanes same addr)
    float ce = xm + __logf(s) - xc;

    if (g == 0) {
      neg_ce[(size_t)b * A_ + a] = pos ? -1.0f : ce;
      if (pos) {
        myPos = 1;
        myCe = ce;
        float4 pl = ((const float4*)pred_loc)[(size_t)b * A_ + a];
        float mx0 = sT[bestM * 5 + 0], my0 = sT[bestM * 5 + 1];
        float mx1 = sT[bestM * 5 + 2], my1 = sT[bestM * 5 + 3];
        float gcx = ((mx0 + mx1) * 0.5f - an.x) / (VAR0 * an.z);
        float gcy = ((my0 + my1) * 0.5f - an.y) / (VAR0 * an.w);
        float gw  = __logf((mx1 - mx0) / an.z) / VAR1;
        float gh  = __logf((my1 - my0) / an.w) / VAR1;
        float d0 = fabsf(pl.x - gcx), d1 = fabsf(pl.y - gcy);
        float d2 = fabsf(pl.z - gw),  d3 = fabsf(pl.w - gh);
        float s0 = d0 < 1.0f ? 0.5f * d0 * d0 : d0 - 0.5f;
        float s1 = d1 < 1.0f ? 0.5f * d1 * d1 : d1 - 0.5f;
        float s2 = d2 < 1.0f ? 0.5f * d2 * d2 : d2 - 0.5f;
        float s3 = d3 < 1.0f ? 0.5f * d3 * d3 : d3 - 0.5f;
        myLoc = s0 + s1 + s2 + s3;
      }
    }
  }

  // block reduce (wave shfl + LDS across 4 waves); partials avoid float atomics
  float rc = myCe, rl = myLoc; int rp = myPos;
  #pragma unroll
  for (int off = 32; off > 0; off >>= 1) {
    rc += __shfl_down(rc, off, 64);
    rl += __shfl_down(rl, off, 64);
    rp += __shfl_down(rp, off, 64);
  }
  __shared__ float swc[4], swl[4];
  __shared__ int swp[4];
  int w = tid >> 6;
  if ((tid & 63) == 0) { swc[w] = rc; swl[w] = rl; swp[w] = rp; }
  __syncthreads();
  if (tid == 0) {
    float tc = swc[0] + swc[1] + swc[2] + swc[3];
    float tl = swl[0] + swl[1] + swl[2] + swl[3];
    int tp = swp[0] + swp[1] + swp[2] + swp[3];
    int pb = blockIdx.y * gridDim.x + blockIdx.x;
    partCe[pb] = tc;
    partLoc[pb] = tl;
    if (tp) atomicAdd(&posCount[b], tp);
  }
}

// ---------------- K3: per-batch exact top-K sum + fused finalize ------------
// 3-pass radix (11/11/10) with fused per-bin count+sum. Each block atomicAdds
// its batch sum into *negAccum (device-scope, coherent); the LAST block to
// finish (doneCount) performs the final reduction. partLoc/partCe/posCount
// were written by the PREVIOUS kernel -> coherent at dispatch boundary.
__global__ __launch_bounds__(256) void k_select(
    const float* __restrict__ neg_ce, const int* __restrict__ posCount,
    const float* __restrict__ partLoc, const float* __restrict__ partCe,
    int* __restrict__ doneCount, float* __restrict__ negAccum,
    float* __restrict__ out) {
  int b = blockIdx.x;
  int tid = threadIdx.x;
  const float* v = neg_ce + (size_t)b * A_;
  int p = posCount[b];
  int cand = A_ - p;
  int K = max(10, min(p * 3, A_ - p));
  if (K > cand) K = cand;

  __shared__ int hist[2048];
  __shared__ float hsum[2048];
  __shared__ int sC8[256];
  __shared__ float sS8[256];
  __shared__ unsigned shPrefix;
  __shared__ int shKrem;
  __shared__ float shSum;
  __shared__ int shAmLast;

  unsigned prefix = 0;
  int Krem = K;
  float sumAcc = 0.0f;

  const int shifts[3] = {21, 10, 0};
  const int widths[3] = {11, 11, 10};

  for (int pass = 0; pass < 3; ++pass) {
    int shift = shifts[pass], width = widths[pass];
    int nb = 1 << width;
    for (int i = tid; i < nb; i += 256) { hist[i] = 0; hsum[i] = 0.0f; }
    __syncthreads();
    for (int i = tid; i < A_; i += 256) {
      float f = v[i];
      if (f >= 0.0f) {                       // positives marked -1.0f; ce >= 0
        unsigned u = __float_as_uint(f);
        bool m = (pass == 0) || ((u >> (shift + width)) == prefix);
        if (m) {
          unsigned d = (u >> shift) & (unsigned)(nb - 1);
          atomicAdd(&hist[d], 1);
          atomicAdd(&hsum[d], f);
        }
      }
    }
    __syncthreads();
    int per = nb >> 8;                       // 8 or 4 bins per thread
    int c8 = 0; float s8 = 0.0f;
    for (int i = 0; i < per; ++i) { c8 += hist[tid * per + i]; s8 += hsum[tid * per + i]; }
    sC8[tid] = c8; sS8[tid] = s8;
    __syncthreads();
    if (tid == 0) {
      int cum = 0; float sa = 0.0f; int t;
      for (t = 255; t >= 0; --t) {
        if (cum + sC8[t] >= Krem) break;
        cum += sC8[t]; sa += sS8[t];
      }
      int d = t * per;
      for (int i = per - 1; i >= 0; --i) {
        int bin = t * per + i;
        if (cum + hist[bin] >= Krem) { d = bin; break; }
        cum += hist[bin]; sa += hsum[bin];
      }
      shPrefix = (prefix << width) | (unsigned)d;
      shKrem = Krem - cum;
      shSum = sumAcc + sa;
    }
    __syncthreads();
    prefix = shPrefix; Krem = shKrem; sumAcc = shSum;
    __syncthreads();
  }

  if (tid == 0) {
    float batchSum = sumAcc + (float)Krem * __uint_as_float(prefix);
    atomicAdd(negAccum, batchSum);
    __threadfence();                         // release: negAccum before done tick
    int prev = atomicAdd(doneCount, 1);
    shAmLast = (prev == B_ - 1) ? 1 : 0;
  }
  __syncthreads();

  if (shAmLast) {
    __threadfence();                         // acquire
    double locS = 0.0, ceS = 0.0;
    int N = 0;
    for (int i = tid; i < NBLK; i += 256) {
      locS += (double)partLoc[i];
      ceS  += (double)partCe[i];
    }
    if (tid < B_) N = posCount[tid];
    #pragma unroll
    for (int off = 32; off > 0; off >>= 1) {
      locS += __shfl_down(locS, off, 64);
      ceS  += __shfl_down(ceS, off, 64);
      N    += __shfl_down(N, off, 64);
    }
    __shared__ double sL[4], sC[4];
    __shared__ int sN[4];
    int w = tid >> 6;
    if ((tid & 63) == 0) { sL[w] = locS; sC[w] = ceS; sN[w] = N; }
    __syncthreads();
    if (tid == 0) {
      double L = sL[0] + sL[1] + sL[2] + sL[3];
      double Cc = sC[0] + sC[1] + sC[2] + sC[3];
      int n = sN[0] + sN[1] + sN[2] + sN[3];
      float G = atomicAdd(negAccum, 0.0f);   // coherent read of all 32 adds
      float fn = (float)n;
      out[0] = (float)((Cc + (double)G) / (double)fn);
      out[1] = (float)(L / (double)fn);
      out[2] = fn;
    }
  }
}

extern "C" void kernel_launch(void* const* d_in, const int* in_sizes, int n_in,
                              void* d_out, int out_size, void* d_ws, size_t ws_size,
                              hipStream_t stream) {
  const float* pred_conf = (const float*)d_in[0];
  const float* pred_loc  = (const float*)d_in[1];
  const float* anchors   = (const float*)d_in[2];
  const float* targets   = (const float*)d_in[3];
  float* out = (float*)d_out;

  char* ws = (char*)d_ws;
  int*   posCount  = (int*)(ws + 0);                   // 128 B
  int*   doneCount = (int*)(ws + 128);                 // 4 B
  float* negAccum  = (float*)(ws + 132);               // 4 B
  int*   bestA     = (int*)(ws + 256);                 // 2560 B
  float* partLoc   = (float*)(ws + 4096);              // 48 KiB
  float* partCe    = (float*)(ws + 4096 + 49152);      // 48 KiB
  float* neg_ce    = (float*)(ws + 131072);            // B*A floats ~3.1 MiB

  k_best_anchor<<<dim3(B_ * M_), 256, 0, stream>>>(anchors, targets, bestA,
                                                   posCount, doneCount, negAccum);
  k_main<<<dim3(GRIDX, B_), 256, 0, stream>>>(pred_conf, pred_loc, anchors, targets,
                                              bestA, neg_ce, partLoc, partCe, posCount);
  k_select<<<dim3(B_), 256, 0, stream>>>(neg_ce, posCount, partLoc, partCe,
                                         doneCount, negAccum, out);
}

// Round 6
// 535.265 us; speedup vs baseline: 1.0511x; 1.0267x over previous
//
#include <hip/hip_runtime.h>

// SSD MultiBox loss, MI355X. B=32 batches, A=24564 anchors, C=81 classes, M=20 targets.
// Outputs: out[0]=class_loss, out[1]=loc_loss/N, out[2]=N  (fp32)
// 3 dispatches: k_best (zeros control) -> k_main (persistent, dbuf pipeline)
//               -> k_select (+fused finalize).

#define B_ 32
#define A_ 24564
#define C_ 81
#define M_ 20

constexpr float THRESH = 0.5f;
constexpr float VAR0 = 0.1f;
constexpr float VAR1 = 0.2f;
constexpr int GRIDX = (A_ + 63) / 64;     // 384 logical 64-row tiles per batch
constexpr int NBLK = GRIDX * B_;          // 12288 partials (one per tile)
constexpr int BLK_PER_BATCH = 24;         // 24 blocks x 16 tiles x 64 rows = 24576 >= A_
constexpr int NPERS = B_ * BLK_PER_BATCH; // 768 persistent blocks = 3/CU
constexpr int TILES_PB = 16;
constexpr int TILE_F4 = (64 * C_) / 4;    // 1296 float4 per full tile

#define AS1 __attribute__((address_space(1)))
#define AS3 __attribute__((address_space(3)))

// ---------------- K1: best anchor per (b, m); block 0 zeros control slots ---
__global__ __launch_bounds__(256) void k_best_anchor(
    const float* __restrict__ anchors, const float* __restrict__ targets,
    int* __restrict__ bestA, int* __restrict__ posCount,
    int* __restrict__ doneCount, float* __restrict__ negAccum) {
  int bm = blockIdx.x;                 // b*M + m
  if (bm == 0) {
    if (threadIdx.x < B_) posCount[threadIdx.x] = 0;
    if (threadIdx.x == B_) *doneCount = 0;
    if (threadIdx.x == B_ + 1) *negAccum = 0.0f;
  }
  const float* t = targets + (size_t)bm * 5;
  float tx0 = t[0], ty0 = t[1], tx1 = t[2], ty1 = t[3];
  float areaT = (tx1 - tx0) * (ty1 - ty0);
  unsigned long long best = 0ull;
  for (int a = threadIdx.x; a < A_; a += 256) {
    float4 an = ((const float4*)anchors)[a];
    float ax0 = an.x - an.z * 0.5f, ay0 = an.y - an.w * 0.5f;
    float ax1 = an.x + an.z * 0.5f, ay1 = an.y + an.w * 0.5f;
    float lx = fmaxf(tx0, ax0), ly = fmaxf(ty0, ay0);
    float rx = fminf(tx1, ax1), ry = fminf(ty1, ay1);
    float w = fmaxf(rx - lx, 0.0f), h = fmaxf(ry - ly, 0.0f);
    float inter = w * h;
    float iou = inter / (areaT + (ax1 - ax0) * (ay1 - ay0) - inter);
    unsigned long long key =
        ((unsigned long long)__float_as_uint(iou) << 32) |
        (unsigned long long)(0xFFFFFFFFu - (unsigned)a);
    best = (key > best) ? key : best;
  }
  __shared__ unsigned long long sh[256];
  sh[threadIdx.x] = best;
  __syncthreads();
  for (int s = 128; s > 0; s >>= 1) {
    if (threadIdx.x < s) {
      unsigned long long o = sh[threadIdx.x + s];
      if (o > sh[threadIdx.x]) sh[threadIdx.x] = o;
    }
    __syncthreads();
  }
  if (threadIdx.x == 0)
    bestA[bm] = (int)(0xFFFFFFFFu - (unsigned)(sh[0] & 0xFFFFFFFFull));
}

// ---------------- K2: persistent double-buffered match+CE+smooth-L1 --------
// 768 blocks, 3/CU (LDS 2x20736B). Block owns 16 contiguous 64-row tiles of
// ONE batch -> targets loaded once, HBM stream is 332KB sequential.
// Per tile: stage(t+1) -> s_waitcnt vmcnt(6) -> s_barrier -> compute(t)
//           -> lgkmcnt(0) -> s_barrier.  Counted vmcnt keeps the next tile's
// 6 loads in flight across the barrier (never drains to 0 mid-loop).
__global__ __launch_bounds__(256) void k_main(
    const float* __restrict__ pred_conf, const float* __restrict__ pred_loc,
    const float* __restrict__ anchors, const float* __restrict__ targets,
    const int* __restrict__ bestA, float* __restrict__ neg_ce,
    float* __restrict__ partLoc, float* __restrict__ partCe,
    int* __restrict__ posCount) {
  __shared__ float sRows[2][64 * C_];      // 2 x 20736 B
  __shared__ float sT[M_ * 5];
  __shared__ int sBA[M_];
  __shared__ float swc[4], swl[4];
  __shared__ int swp[4];

  int tid = threadIdx.x;
  int blk = blockIdx.x;
  int b = blk / BLK_PER_BATCH;
  int chunk = blk % BLK_PER_BATCH;
  int row_base = chunk * (TILES_PB * 64);  // 1024 rows per block
  const float* confB = pred_conf + (size_t)b * A_ * C_;

  // stage tile (row offset a0) into buffer p: exactly 6 uniform issues/thread.
  // issues 0..4: idx = j*256+tid (0..1279); issue 5: idx = 1040+tid (1040..1295,
  // overlapping re-write of identical data keeps per-wave vmcnt counts equal).
  // Tail tiles clamp the SOURCE index (dест stays in-buffer; rows >= A_ unused).
  auto stage = [&](int a0, int p) {
    int nf4 = (min(64, A_ - a0) * C_) >> 2;            // 1296 or 1053
    const float4* src = (const float4*)(confB + (size_t)a0 * C_);
    #pragma unroll
    for (int j = 0; j < 6; ++j) {
      int idx = (j < 5) ? (j * 256 + tid) : (1040 + tid);
      int sidx = idx < nf4 ? idx : (nf4 - 1);
      __builtin_amdgcn_global_load_lds(
          (const AS1 unsigned int*)(src + sidx),
          (AS3 unsigned int*)(&sRows[p][idx * 4]), 16, 0, 0);
    }
  };

  stage(row_base, 0);                       // prologue: tile 0 in flight
  if (tid < M_ * 5) sT[tid] = targets[(size_t)b * M_ * 5 + tid];
  if (tid < M_) sBA[tid] = bestA[b * M_ + tid];
  __syncthreads();                          // one-time full drain (tile 0 + sT)

  int g = tid & 3;
  int q = tid >> 2;

  for (int t = 0; t < TILES_PB; ++t) {
    int a0 = row_base + t * 64;
    int p = t & 1;
    if (t + 1 < TILES_PB) {
      stage(row_base + (t + 1) * 64, p ^ 1);
      asm volatile("s_waitcnt vmcnt(6)" ::: "memory");  // tile t landed; t+1 in flight
    } else {
      asm volatile("s_waitcnt vmcnt(0)" ::: "memory");
    }
    __builtin_amdgcn_s_barrier();           // BAR1: all waves' tile-t loads done
    __builtin_amdgcn_sched_barrier(0);

    int a = a0 + q;
    bool active = (a < A_);
    float myCe = 0.0f, myLoc = 0.0f;
    int myPos = 0;

    if (active) {
      float4 an = ((const float4*)anchors)[a];
      float ax0 = an.x - an.z * 0.5f, ay0 = an.y - an.w * 0.5f;
      float ax1 = an.x + an.z * 0.5f, ay1 = an.y + an.w * 0.5f;
      float areaA = (ax1 - ax0) * (ay1 - ay0);

      // lane-split argmax over M (5 targets/lane), packed-u64 reduce;
      // ties -> smallest m == numpy first-max.
      unsigned long long key = 0ull;
      #pragma unroll
      for (int k = 0; k < 5; ++k) {
        int m = g + 4 * k;
        float tx0 = sT[m * 5 + 0], ty0 = sT[m * 5 + 1];
        float tx1 = sT[m * 5 + 2], ty1 = sT[m * 5 + 3];
        float lx = fmaxf(tx0, ax0), ly = fmaxf(ty0, ay0);
        float rx = fminf(tx1, ax1), ry = fminf(ty1, ay1);
        float w = fmaxf(rx - lx, 0.0f), h = fmaxf(ry - ly, 0.0f);
        float inter = w * h;
        float areaT = (tx1 - tx0) * (ty1 - ty0);
        float iou = inter / (areaT + areaA - inter);
        unsigned long long kk =
            ((unsigned long long)__float_as_uint(iou) << 32) |
            (unsigned long long)(0xFFFFFFFFu - (unsigned)m);
        key = (kk > key) ? kk : key;
      }
      {
        unsigned long long o = __shfl_xor(key, 1, 64);
        key = (o > key) ? o : key;
        o = __shfl_xor(key, 2, 64);
        key = (o > key) ? o : key;
      }
      float bestIou = __uint_as_float((unsigned)(key >> 32));
      int bestM = (int)(0xFFFFFFFFu - (unsigned)(key & 0xFFFFFFFFull));

      // guarantee override, ascending m => last-m-wins
      #pragma unroll
      for (int m = 0; m < M_; ++m)
        if (sBA[m] == a) { bestIou = 2.0f; bestM = m; }

      bool pos = (bestIou >= THRESH);
      int c = pos ? ((int)sT[bestM * 5 + 4] + 1) : 0;

      // LSE over 81 classes split across 4 lanes
      const float* row = &sRows[p][q * C_];
      float x[20];
      #pragma unroll
      for (int k = 0; k < 20; ++k) x[k] = row[g + 4 * k];
      float r80 = row[80];
      float v80 = (g == 0) ? r80 : -1e30f;

      float xm = v80;
      #pragma unroll
      for (int k = 0; k < 20; ++k) xm = fmaxf(xm, x[k]);
      xm = fmaxf(xm, __shfl_xor(xm, 1, 64));
      xm = fmaxf(xm, __shfl_xor(xm, 2, 64));

      float s = __expf(v80 - xm);
      #pragma unroll
      for (int k = 0; k < 20; ++k) s += __expf(x[k] - xm);
      s += __shfl_xor(s, 1, 64);
      s += __shfl_xor(s, 2, 64);

      float xc = row[c];                   // LDS broadcast (4 lanes same addr)
      float ce = xm + __logf(s) - xc;

      if (g == 0) {
        neg_ce[(size_t)b * A_ + a] = pos ? -1.0f : ce;
        if (pos) {
          myPos = 1;
          myCe = ce;
          float4 pl = ((const float4*)pred_loc)[(size_t)b * A_ + a];
          float mx0 = sT[bestM * 5 + 0], my0 = sT[bestM * 5 + 1];
          float mx1 = sT[bestM * 5 + 2], my1 = sT[bestM * 5 + 3];
          float gcx = ((mx0 + mx1) * 0.5f - an.x) / (VAR0 * an.z);
          float gcy = ((my0 + my1) * 0.5f - an.y) / (VAR0 * an.w);
          float gw  = __logf((mx1 - mx0) / an.z) / VAR1;
          float gh  = __logf((my1 - my0) / an.w) / VAR1;
          float d0 = fabsf(pl.x - gcx), d1 = fabsf(pl.y - gcy);
          float d2 = fabsf(pl.z - gw),  d3 = fabsf(pl.w - gh);
          float s0 = d0 < 1.0f ? 0.5f * d0 * d0 : d0 - 0.5f;
          float s1 = d1 < 1.0f ? 0.5f * d1 * d1 : d1 - 0.5f;
          float s2 = d2 < 1.0f ? 0.5f * d2 * d2 : d2 - 0.5f;
          float s3 = d3 < 1.0f ? 0.5f * d3 * d3 : d3 - 0.5f;
          myLoc = s0 + s1 + s2 + s3;
        }
      }
    }

    // per-tile block reduce; scratch is disjoint from sRows, race-free by
    // the barrier pairing (tid0 reads finish before any wave passes BAR1(t+1)).
    float rc = myCe, rl = myLoc; int rp = myPos;
    #pragma unroll
    for (int off = 32; off > 0; off >>= 1) {
      rc += __shfl_down(rc, off, 64);
      rl += __shfl_down(rl, off, 64);
      rp += __shfl_down(rp, off, 64);
    }
    int w = tid >> 6;
    if ((tid & 63) == 0) { swc[w] = rc; swl[w] = rl; swp[w] = rp; }
    asm volatile("s_waitcnt lgkmcnt(0)" ::: "memory");
    __builtin_amdgcn_s_barrier();           // BAR2: reads of buf p done, scratch visible
    if (tid == 0) {
      float tc = swc[0] + swc[1] + swc[2] + swc[3];
      float tl = swl[0] + swl[1] + swl[2] + swl[3];
      int tp = swp[0] + swp[1] + swp[2] + swp[3];
      int pb = b * GRIDX + (row_base >> 6) + t;   // global tile id
      partCe[pb] = tc;
      partLoc[pb] = tl;
      if (tp) atomicAdd(&posCount[b], tp);
    }
  }
}

// ---------------- K3: per-batch exact top-K sum + fused finalize ------------
__global__ __launch_bounds__(256) void k_select(
    const float* __restrict__ neg_ce, const int* __restrict__ posCount,
    const float* __restrict__ partLoc, const float* __restrict__ partCe,
    int* __restrict__ doneCount, float* __restrict__ negAccum,
    float* __restrict__ out) {
  int b = blockIdx.x;
  int tid = threadIdx.x;
  const float* v = neg_ce + (size_t)b * A_;
  int p = posCount[b];
  int cand = A_ - p;
  int K = max(10, min(p * 3, A_ - p));
  if (K > cand) K = cand;

  __shared__ int hist[2048];
  __shared__ float hsum[2048];
  __shared__ int sC8[256];
  __shared__ float sS8[256];
  __shared__ unsigned shPrefix;
  __shared__ int shKrem;
  __shared__ float shSum;
  __shared__ int shAmLast;

  unsigned prefix = 0;
  int Krem = K;
  float sumAcc = 0.0f;

  const int shifts[3] = {21, 10, 0};
  const int widths[3] = {11, 11, 10};

  for (int pass = 0; pass < 3; ++pass) {
    int shift = shifts[pass], width = widths[pass];
    int nb = 1 << width;
    for (int i = tid; i < nb; i += 256) { hist[i] = 0; hsum[i] = 0.0f; }
    __syncthreads();
    for (int i = tid; i < A_; i += 256) {
      float f = v[i];
      if (f >= 0.0f) {
        unsigned u = __float_as_uint(f);
        bool m = (pass == 0) || ((u >> (shift + width)) == prefix);
        if (m) {
          unsigned d = (u >> shift) & (unsigned)(nb - 1);
          atomicAdd(&hist[d], 1);
          atomicAdd(&hsum[d], f);
        }
      }
    }
    __syncthreads();
    int per = nb >> 8;
    int c8 = 0; float s8 = 0.0f;
    for (int i = 0; i < per; ++i) { c8 += hist[tid * per + i]; s8 += hsum[tid * per + i]; }
    sC8[tid] = c8; sS8[tid] = s8;
    __syncthreads();
    if (tid == 0) {
      int cum = 0; float sa = 0.0f; int t;
      for (t = 255; t >= 0; --t) {
        if (cum + sC8[t] >= Krem) break;
        cum += sC8[t]; sa += sS8[t];
      }
      int d = t * per;
      for (int i = per - 1; i >= 0; --i) {
        int bin = t * per + i;
        if (cum + hist[bin] >= Krem) { d = bin; break; }
        cum += hist[bin]; sa += hsum[bin];
      }
      shPrefix = (prefix << width) | (unsigned)d;
      shKrem = Krem - cum;
      shSum = sumAcc + sa;
    }
    __syncthreads();
    prefix = shPrefix; Krem = shKrem; sumAcc = shSum;
    __syncthreads();
  }

  if (tid == 0) {
    float batchSum = sumAcc + (float)Krem * __uint_as_float(prefix);
    atomicAdd(negAccum, batchSum);
    __threadfence();
    int prev = atomicAdd(doneCount, 1);
    shAmLast = (prev == B_ - 1) ? 1 : 0;
  }
  __syncthreads();

  if (shAmLast) {
    __threadfence();
    double locS = 0.0, ceS = 0.0;
    int N = 0;
    for (int i = tid; i < NBLK; i += 256) {
      locS += (double)partLoc[i];
      ceS  += (double)partCe[i];
    }
    if (tid < B_) N = posCount[tid];
    #pragma unroll
    for (int off = 32; off > 0; off >>= 1) {
      locS += __shfl_down(locS, off, 64);
      ceS  += __shfl_down(ceS, off, 64);
      N    += __shfl_down(N, off, 64);
    }
    __shared__ double sL[4], sC[4];
    __shared__ int sN[4];
    int w = tid >> 6;
    if ((tid & 63) == 0) { sL[w] = locS; sC[w] = ceS; sN[w] = N; }
    __syncthreads();
    if (tid == 0) {
      double L = sL[0] + sL[1] + sL[2] + sL[3];
      double Cc = sC[0] + sC[1] + sC[2] + sC[3];
      int n = sN[0] + sN[1] + sN[2] + sN[3];
      float G = atomicAdd(negAccum, 0.0f);
      float fn = (float)n;
      out[0] = (float)((Cc + (double)G) / (double)fn);
      out[1] = (float)(L / (double)fn);
      out[2] = fn;
    }
  }
}

extern "C" void kernel_launch(void* const* d_in, const int* in_sizes, int n_in,
                              void* d_out, int out_size, void* d_ws, size_t ws_size,
                              hipStream_t stream) {
  const float* pred_conf = (const float*)d_in[0];
  const float* pred_loc  = (const float*)d_in[1];
  const float* anchors   = (const float*)d_in[2];
  const float* targets   = (const float*)d_in[3];
  float* out = (float*)d_out;

  char* ws = (char*)d_ws;
  int*   posCount  = (int*)(ws + 0);                   // 128 B
  int*   doneCount = (int*)(ws + 128);                 // 4 B
  float* negAccum  = (float*)(ws + 132);               // 4 B
  int*   bestA     = (int*)(ws + 256);                 // 2560 B
  float* partLoc   = (float*)(ws + 4096);              // 48 KiB
  float* partCe    = (float*)(ws + 4096 + 49152);      // 48 KiB
  float* neg_ce    = (float*)(ws + 131072);            // B*A floats ~3.1 MiB

  k_best_anchor<<<dim3(B_ * M_), 256, 0, stream>>>(anchors, targets, bestA,
                                                   posCount, doneCount, negAccum);
  k_main<<<dim3(NPERS), 256, 0, stream>>>(pred_conf, pred_loc, anchors, targets,
                                          bestA, neg_ce, partLoc, partCe, posCount);
  k_select<<<dim3(B_), 256, 0, stream>>>(neg_ce, posCount, partLoc, partCe,
                                         doneCount, negAccum, out);
}